// Round 1
// baseline (31664.005 us; speedup 1.0000x reference)
//
#include <hip/hip_runtime.h>

// ElmanRNN: out[b][s][h] = tanh(x[b][s]@W_ih^T + b_ih + b_hh + h_prev@W_hh^T)
// B=64 S=1024 I=H=512, fp32 in/out.
//
// Kernel 1: x_proj GEMM (bf16 MFMA, 128x128 tile) written IN-PLACE into d_out.
// Kernel 2: persistent recurrence, 256 WGs = 64 batches x 4 row-tiles,
//           W_hh tile held in VGPRs as f16 pairs, 4-WG exchange per step via
//           agent-scope atomics + monotonic flags (double-buffered by parity).

typedef _Float16 f16;
typedef _Float16 f16x2 __attribute__((ext_vector_type(2)));
typedef short    s16x8 __attribute__((ext_vector_type(8)));
typedef float    f32x4 __attribute__((ext_vector_type(4)));

#define NB 64
#define NS 1024
#define NI 512
#define NH 512

__device__ __forceinline__ short f2bf(float f) {
  unsigned u = __builtin_bit_cast(unsigned, f);
  u = (u + 0x7FFFu + ((u >> 16) & 1u)) >> 16;   // RNE
  return (short)u;
}

#if __has_builtin(__builtin_amdgcn_fdot2)
__device__ __forceinline__ float dot2(f16x2 a, f16x2 b, float c) {
  return __builtin_amdgcn_fdot2(a, b, c, false);
}
#else
__device__ __forceinline__ float dot2(f16x2 a, f16x2 b, float c) {
  return c + (float)a.x * (float)b.x + (float)a.y * (float)b.y;
}
#endif

// ---------------- Kernel 1: x_proj = x @ W_ih^T + (b_ih + b_hh) ----------------
#define BM 128
#define BN 128
#define BK 32
#define KP 40   // padded row stride in bf16 elems (80B: 16B-aligned, odd 16B-count)

__global__ __launch_bounds__(256) void xproj_gemm(
    const float* __restrict__ X, const float* __restrict__ W,
    const float* __restrict__ bih, const float* __restrict__ bhh,
    float* __restrict__ out)
{
  __shared__ short As[BM * KP];
  __shared__ short Bs[BN * KP];
  const int t  = threadIdx.x;
  const int mt = blockIdx.x >> 2;      // 512 m-tiles
  const int nt = blockIdx.x & 3;       // 4 n-tiles
  const int m0 = mt * BM, n0 = nt * BN;
  const int lane = t & 63, wv = t >> 6;
  const int wm = (wv & 1) * 64, wn = (wv >> 1) * 64;
  const int l15 = lane & 15, l4 = lane >> 4;

  const int sr = t >> 1;               // staging row 0..127
  const int sk = (t & 1) * 16;         // staging col 0/16
  const float* xa = X + (size_t)(m0 + sr) * NI + sk;
  const float* wa = W + (size_t)(n0 + sr) * NI + sk;
  short* asw = &As[sr * KP + sk];
  short* bsw = &Bs[sr * KP + sk];

  f32x4 acc[4][4];
  #pragma unroll
  for (int i = 0; i < 4; ++i)
    #pragma unroll
    for (int j = 0; j < 4; ++j)
      acc[i][j] = (f32x4){0.f, 0.f, 0.f, 0.f};

  for (int kt = 0; kt < NI; kt += BK) {
    float4 a0 = *(const float4*)(xa + kt);
    float4 a1 = *(const float4*)(xa + kt + 4);
    float4 a2 = *(const float4*)(xa + kt + 8);
    float4 a3 = *(const float4*)(xa + kt + 12);
    float4 b0 = *(const float4*)(wa + kt);
    float4 b1 = *(const float4*)(wa + kt + 4);
    float4 b2 = *(const float4*)(wa + kt + 8);
    float4 b3 = *(const float4*)(wa + kt + 12);
    s16x8 av0 = { f2bf(a0.x), f2bf(a0.y), f2bf(a0.z), f2bf(a0.w),
                  f2bf(a1.x), f2bf(a1.y), f2bf(a1.z), f2bf(a1.w) };
    s16x8 av1 = { f2bf(a2.x), f2bf(a2.y), f2bf(a2.z), f2bf(a2.w),
                  f2bf(a3.x), f2bf(a3.y), f2bf(a3.z), f2bf(a3.w) };
    s16x8 bv0 = { f2bf(b0.x), f2bf(b0.y), f2bf(b0.z), f2bf(b0.w),
                  f2bf(b1.x), f2bf(b1.y), f2bf(b1.z), f2bf(b1.w) };
    s16x8 bv1 = { f2bf(b2.x), f2bf(b2.y), f2bf(b2.z), f2bf(b2.w),
                  f2bf(b3.x), f2bf(b3.y), f2bf(b3.z), f2bf(b3.w) };

    __syncthreads();                   // prior iter's frag reads done
    *(s16x8*)asw       = av0;
    *(s16x8*)(asw + 8) = av1;
    *(s16x8*)bsw       = bv0;
    *(s16x8*)(bsw + 8) = bv1;
    __syncthreads();

    s16x8 af[4], bf[4];
    #pragma unroll
    for (int mi = 0; mi < 4; ++mi)
      af[mi] = *(const s16x8*)&As[(wm + mi * 16 + l15) * KP + l4 * 8];
    #pragma unroll
    for (int ni = 0; ni < 4; ++ni)
      bf[ni] = *(const s16x8*)&Bs[(wn + ni * 16 + l15) * KP + l4 * 8];
    #pragma unroll
    for (int mi = 0; mi < 4; ++mi)
      #pragma unroll
      for (int ni = 0; ni < 4; ++ni)
        acc[mi][ni] = __builtin_amdgcn_mfma_f32_16x16x32_bf16(
            af[mi], bf[ni], acc[mi][ni], 0, 0, 0);
  }

  #pragma unroll
  for (int ni = 0; ni < 4; ++ni) {
    const int nloc = n0 + wn + ni * 16 + l15;
    const float bias = bih[nloc] + bhh[nloc];
    #pragma unroll
    for (int mi = 0; mi < 4; ++mi) {
      const int mrow = m0 + wm + mi * 16 + l4 * 4;
      #pragma unroll
      for (int j = 0; j < 4; ++j)
        out[(size_t)(mrow + j) * NH + nloc] = acc[mi][ni][j] + bias;
    }
  }
}

// ---------------- Kernel 2: persistent recurrence ----------------
// Grid 256 = tile*64 + b  (peers of batch b differ by 64 => same XCD under %8)
// Each WG: 256 threads; lane t: local row r=t>>1 (0..127), k-half = t&1.
// W_hh[tile*128+r][khalf*256 .. +256) lives in w[128] f16x2 VGPRs.

__global__ __launch_bounds__(256, 1) void rnn_steps(
    const float* __restrict__ Whh, float* __restrict__ out,
    unsigned* __restrict__ flags, unsigned* __restrict__ hpair)
{
  const int bid  = blockIdx.x;
  const int tile = bid >> 6;
  const int b    = bid & 63;
  const int t    = threadIdx.x;
  const int r    = t >> 1;
  const int half = t & 1;
  const int grow = tile * 128 + r;

  f16x2 w[128];
  {
    const float4* wp = (const float4*)(Whh + (size_t)grow * NH + half * 256);
    #pragma unroll
    for (int j = 0; j < 64; ++j) {
      float4 f = wp[j];
      f16x2 p0 = { (f16)f.x, (f16)f.y };
      f16x2 p1 = { (f16)f.z, (f16)f.w };
      w[2 * j]     = p0;
      w[2 * j + 1] = p1;
    }
  }

  __shared__ f16x2 hL[256];            // h_{s-1} as 256 f16 pairs
  {
    f16x2 z = { (f16)0.f, (f16)0.f };
    hL[t] = z;
  }

  float* outp = out + (size_t)b * (NS * NH) + grow;
  float xpv = (half == 0) ? outp[0] : 0.f;          // xp for s=0
  unsigned* myflag = flags + (b * 4 + tile) * 16;
  __syncthreads();

  for (int s = 0; s < NS; ++s) {
    float acc0 = 0.f, acc1 = 0.f, acc2 = 0.f, acc3 = 0.f;
    const f16x2* hb = &hL[half * 128];
    #pragma unroll
    for (int j = 0; j < 128; j += 4) {
      acc0 = dot2(w[j + 0], hb[j + 0], acc0);
      acc1 = dot2(w[j + 1], hb[j + 1], acc1);
      acc2 = dot2(w[j + 2], hb[j + 2], acc2);
      acc3 = dot2(w[j + 3], hb[j + 3], acc3);
    }
    float y = (acc0 + acc1) + (acc2 + acc3);
    y += __shfl_xor(y, 1);                           // combine k-halves
    const float hv  = tanhf(xpv + y);                // valid in even lanes
    const float hvo = __shfl_xor(hv, 2);             // row pair partner
    f16x2 prv = { (f16)hv, (f16)hvo };
    const unsigned pu = __builtin_bit_cast(unsigned, prv);

    if (half == 0)
      outp[(size_t)s * NH] = hv;                     // final output h_s
    if ((t & 3) == 0)                                // own piece -> exchange buf
      __hip_atomic_store(&hpair[(s & 1) * 16384 + b * 256 + tile * 64 + (t >> 2)],
                         pu, __ATOMIC_RELAXED, __HIP_MEMORY_SCOPE_AGENT);
    __threadfence();                                 // each wave drains its stores
    __syncthreads();                                 // all waves' data visible
    if (t == 0)
      __hip_atomic_store(myflag, (unsigned)(s + 1),
                         __ATOMIC_RELAXED, __HIP_MEMORY_SCOPE_AGENT);
    if (half == 0 && s < NS - 1)
      xpv = outp[(size_t)(s + 1) * NH];              // prefetch next xp (hides under exchange)
    if (t >= 1 && t <= 3) {                          // 3 lanes spin on 3 peers
      const unsigned* pf = flags + (b * 4 + ((tile + t) & 3)) * 16;
      while (__hip_atomic_load(pf, __ATOMIC_RELAXED, __HIP_MEMORY_SCOPE_AGENT)
             < (unsigned)(s + 1)) {}
    }
    __syncthreads();
    __threadfence();                                 // acquire side
    if ((t & 3) == 0)                                // own piece direct to LDS
      hL[tile * 64 + (t >> 2)] = __builtin_bit_cast(f16x2, pu);
    if (t < 192) {                                   // 3 peer pieces (64 pairs each)
      const int p = (tile + 1 + (t >> 6)) & 3;
      unsigned v = __hip_atomic_load(&hpair[(s & 1) * 16384 + b * 256 + p * 64 + (t & 63)],
                                     __ATOMIC_RELAXED, __HIP_MEMORY_SCOPE_AGENT);
      hL[p * 64 + (t & 63)] = __builtin_bit_cast(f16x2, v);
    }
    __syncthreads();
  }
}

// ---------------- launch ----------------
extern "C" void kernel_launch(void* const* d_in, const int* in_sizes, int n_in,
                              void* d_out, int out_size, void* d_ws, size_t ws_size,
                              hipStream_t stream) {
  const float* x   = (const float*)d_in[0];
  const float* Wih = (const float*)d_in[1];
  const float* Whh = (const float*)d_in[2];
  const float* bih = (const float*)d_in[3];
  const float* bhh = (const float*)d_in[4];
  float* out = (float*)d_out;

  // ws layout: [0,16KB) flags (64 batches x 4 tiles x 64B pad), [16KB,+128KB) h exchange
  unsigned* flags = (unsigned*)d_ws;
  unsigned* hpair = (unsigned*)((char*)d_ws + 16384);

  hipMemsetAsync(d_ws, 0, 16384, stream);  // flags must be < 1 at every replay

  xproj_gemm<<<dim3((NB * NS / BM) * (NH / BN)), dim3(256), 0, stream>>>(
      x, Wih, bih, bhh, out);
  rnn_steps<<<dim3(256), dim3(256), 0, stream>>>(Whh, out, flags, hpair);
}

// Round 2
// 1589.908 us; speedup vs baseline: 19.9156x; 19.9156x over previous
//
#include <hip/hip_runtime.h>

// ElmanRNN: out[b][s][h] = tanh(x[b][s]@W_ih^T + b_ih + b_hh + h_prev@W_hh^T)
// B=64 S=1024 I=H=512, fp32 in/out.
//
// Kernel 1: x_proj GEMM (bf16 MFMA, 128x128 tile) written IN-PLACE into d_out.
// Kernel 2: recurrence with NO cross-WG communication: 64 WGs (1 per batch),
//           512 threads each own one full h-row; W_hh row split 432 cols in
//           VGPRs (216 f16x2) + 80 cols in LDS (80KB); h double-buffered in
//           LDS (broadcast reads); one __syncthreads per step.

typedef _Float16 f16;
typedef _Float16 f16x2 __attribute__((ext_vector_type(2)));
typedef _Float16 f16x8 __attribute__((ext_vector_type(8)));
typedef short    s16x8 __attribute__((ext_vector_type(8)));
typedef float    f32x4 __attribute__((ext_vector_type(4)));

#define NB 64
#define NS 1024
#define NI 512
#define NH 512

__device__ __forceinline__ short f2bf(float f) {
  unsigned u = __builtin_bit_cast(unsigned, f);
  u = (u + 0x7FFFu + ((u >> 16) & 1u)) >> 16;   // RNE
  return (short)u;
}

#if __has_builtin(__builtin_amdgcn_fdot2)
__device__ __forceinline__ float dot2(f16x2 a, f16x2 b, float c) {
  return __builtin_amdgcn_fdot2(a, b, c, false);
}
#else
__device__ __forceinline__ float dot2(f16x2 a, f16x2 b, float c) {
  return c + (float)a.x * (float)b.x + (float)a.y * (float)b.y;
}
#endif

__device__ __forceinline__ float tanh_fast(float x) {
  // tanh(x) = 1 - 2/(exp(2x)+1), exp via v_exp_f32 (2^x)
#if __has_builtin(__builtin_amdgcn_exp2f)
  float e = __builtin_amdgcn_exp2f(x * 2.8853900817779268f);  // 2*log2(e)
#else
  float e = exp2f(x * 2.8853900817779268f);
#endif
#if __has_builtin(__builtin_amdgcn_rcpf)
  return 1.f - 2.f * __builtin_amdgcn_rcpf(e + 1.f);
#else
  return 1.f - 2.f / (e + 1.f);
#endif
}

// ---------------- Kernel 1: x_proj = x @ W_ih^T + (b_ih + b_hh) ----------------
#define BM 128
#define BN 128
#define BK 32
#define KP 40   // padded row stride in bf16 elems

__global__ __launch_bounds__(256) void xproj_gemm(
    const float* __restrict__ X, const float* __restrict__ W,
    const float* __restrict__ bih, const float* __restrict__ bhh,
    float* __restrict__ out)
{
  __shared__ short As[BM * KP];
  __shared__ short Bs[BN * KP];
  const int t  = threadIdx.x;
  const int mt = blockIdx.x >> 2;
  const int nt = blockIdx.x & 3;
  const int m0 = mt * BM, n0 = nt * BN;
  const int lane = t & 63, wv = t >> 6;
  const int wm = (wv & 1) * 64, wn = (wv >> 1) * 64;
  const int l15 = lane & 15, l4 = lane >> 4;

  const int sr = t >> 1;
  const int sk = (t & 1) * 16;
  const float* xa = X + (size_t)(m0 + sr) * NI + sk;
  const float* wa = W + (size_t)(n0 + sr) * NI + sk;
  short* asw = &As[sr * KP + sk];
  short* bsw = &Bs[sr * KP + sk];

  f32x4 acc[4][4];
  #pragma unroll
  for (int i = 0; i < 4; ++i)
    #pragma unroll
    for (int j = 0; j < 4; ++j)
      acc[i][j] = (f32x4){0.f, 0.f, 0.f, 0.f};

  for (int kt = 0; kt < NI; kt += BK) {
    float4 a0 = *(const float4*)(xa + kt);
    float4 a1 = *(const float4*)(xa + kt + 4);
    float4 a2 = *(const float4*)(xa + kt + 8);
    float4 a3 = *(const float4*)(xa + kt + 12);
    float4 b0 = *(const float4*)(wa + kt);
    float4 b1 = *(const float4*)(wa + kt + 4);
    float4 b2 = *(const float4*)(wa + kt + 8);
    float4 b3 = *(const float4*)(wa + kt + 12);
    s16x8 av0 = { f2bf(a0.x), f2bf(a0.y), f2bf(a0.z), f2bf(a0.w),
                  f2bf(a1.x), f2bf(a1.y), f2bf(a1.z), f2bf(a1.w) };
    s16x8 av1 = { f2bf(a2.x), f2bf(a2.y), f2bf(a2.z), f2bf(a2.w),
                  f2bf(a3.x), f2bf(a3.y), f2bf(a3.z), f2bf(a3.w) };
    s16x8 bv0 = { f2bf(b0.x), f2bf(b0.y), f2bf(b0.z), f2bf(b0.w),
                  f2bf(b1.x), f2bf(b1.y), f2bf(b1.z), f2bf(b1.w) };
    s16x8 bv1 = { f2bf(b2.x), f2bf(b2.y), f2bf(b2.z), f2bf(b2.w),
                  f2bf(b3.x), f2bf(b3.y), f2bf(b3.z), f2bf(b3.w) };

    __syncthreads();
    *(s16x8*)asw       = av0;
    *(s16x8*)(asw + 8) = av1;
    *(s16x8*)bsw       = bv0;
    *(s16x8*)(bsw + 8) = bv1;
    __syncthreads();

    s16x8 af[4], bf[4];
    #pragma unroll
    for (int mi = 0; mi < 4; ++mi)
      af[mi] = *(const s16x8*)&As[(wm + mi * 16 + l15) * KP + l4 * 8];
    #pragma unroll
    for (int ni = 0; ni < 4; ++ni)
      bf[ni] = *(const s16x8*)&Bs[(wn + ni * 16 + l15) * KP + l4 * 8];
    #pragma unroll
    for (int mi = 0; mi < 4; ++mi)
      #pragma unroll
      for (int ni = 0; ni < 4; ++ni)
        acc[mi][ni] = __builtin_amdgcn_mfma_f32_16x16x32_bf16(
            af[mi], bf[ni], acc[mi][ni], 0, 0, 0);
  }

  #pragma unroll
  for (int ni = 0; ni < 4; ++ni) {
    const int nloc = n0 + wn + ni * 16 + l15;
    const float bias = bih[nloc] + bhh[nloc];
    #pragma unroll
    for (int mi = 0; mi < 4; ++mi) {
      const int mrow = m0 + wm + mi * 16 + l4 * 4;
      #pragma unroll
      for (int j = 0; j < 4; ++j)
        out[(size_t)(mrow + j) * NH + nloc] = acc[mi][ni][j] + bias;
    }
  }
}

// ---------------- Kernel 2: per-batch recurrence, zero cross-WG sync ----------
// Grid 64 (1 WG per batch), 512 threads. Thread t owns h-row r = t.
// W_hh[t][0..431] in VGPRs (216 f16x2), W_hh[t][432..511] in LDS wq (80KB).
// h_{s} double-buffered in LDS as 256 f16x2 (1KB x2), broadcast reads.

#define KV 216                 // f16x2 pairs of W per row in VGPRs (k < 432)
#define KQ 10                  // f16x8 chunks per row in LDS (k in [432,512))

__global__ __launch_bounds__(512, 2) void rnn_steps(
    const float* __restrict__ Whh, float* __restrict__ out)
{
  extern __shared__ f16x8 wq_raw[];                // [KQ][512]
  f16x8 (*wq)[512] = (f16x8(*)[512])wq_raw;
  __shared__ __align__(16) f16x2 hbuf[2][256];

  const int b = blockIdx.x;
  const int t = threadIdx.x;

  // ---- load W row t: cols 0..431 -> VGPR, 432..511 -> LDS ----
  f16x2 wv[KV];
  const float4* row4 = (const float4*)(Whh + (size_t)t * NH);
  #pragma unroll
  for (int j = 0; j < 108; ++j) {
    float4 f = row4[j];
    wv[2 * j]     = (f16x2){ (f16)f.x, (f16)f.y };
    wv[2 * j + 1] = (f16x2){ (f16)f.z, (f16)f.w };
  }
  #pragma unroll
  for (int q = 0; q < KQ; ++q) {
    float4 fa = row4[108 + 2 * q];
    float4 fb = row4[109 + 2 * q];
    wq[q][t] = (f16x8){ (f16)fa.x, (f16)fa.y, (f16)fa.z, (f16)fa.w,
                        (f16)fb.x, (f16)fb.y, (f16)fb.z, (f16)fb.w };
  }
  if (t < 256) {
    hbuf[0][t] = (f16x2){ (f16)0.f, (f16)0.f };
  }

  float* outp = out + (size_t)b * (NS * NH) + t;
  float xpv = outp[0];                       // xp for s=0 (xproj output)
  __syncthreads();

  for (int s = 0; s < NS; ++s) {
    // prefetch next step's xp early: latency hides under the dot product
    float xq = 0.f;
    if (s + 1 < NS) xq = outp[(size_t)(s + 1) * NH];

    const f16x2* hb = hbuf[s & 1];
    float a0 = 0.f, a1 = 0.f, a2 = 0.f, a3 = 0.f;
    #pragma unroll
    for (int c = 0; c < 54; ++c) {            // k in [0,432): W from VGPRs
      f16x8 hc = *(const f16x8*)&hb[4 * c];   // 16B broadcast read
      f16x2 h0 = { hc[0], hc[1] }, h1 = { hc[2], hc[3] };
      f16x2 h2 = { hc[4], hc[5] }, h3 = { hc[6], hc[7] };
      a0 = dot2(wv[4 * c + 0], h0, a0);
      a1 = dot2(wv[4 * c + 1], h1, a1);
      a2 = dot2(wv[4 * c + 2], h2, a2);
      a3 = dot2(wv[4 * c + 3], h3, a3);
    }
    #pragma unroll
    for (int q = 0; q < KQ; ++q) {            // k in [432,512): W from LDS
      f16x8 wc = wq[q][t];                    // lane-consecutive 16B
      f16x8 hc = *(const f16x8*)&hb[KV + 4 * q];
      f16x2 w0 = { wc[0], wc[1] }, w1 = { wc[2], wc[3] };
      f16x2 w2 = { wc[4], wc[5] }, w3 = { wc[6], wc[7] };
      f16x2 h0 = { hc[0], hc[1] }, h1 = { hc[2], hc[3] };
      f16x2 h2 = { hc[4], hc[5] }, h3 = { hc[6], hc[7] };
      a0 = dot2(w0, h0, a0);
      a1 = dot2(w1, h1, a1);
      a2 = dot2(w2, h2, a2);
      a3 = dot2(w3, h3, a3);
    }
    const float y = (a0 + a1) + (a2 + a3);
    const float hval = tanh_fast(xpv + y);

    outp[(size_t)s * NH] = hval;              // coalesced 2KB store
    const float hnb = __shfl_xor(hval, 1);    // row-pair partner
    if ((t & 1) == 0)
      hbuf[(s + 1) & 1][t >> 1] = (f16x2){ (f16)hval, (f16)hnb };
    xpv = xq;
    __syncthreads();                          // next buffer ready
  }
}

// ---------------- launch ----------------
extern "C" void kernel_launch(void* const* d_in, const int* in_sizes, int n_in,
                              void* d_out, int out_size, void* d_ws, size_t ws_size,
                              hipStream_t stream) {
  const float* x   = (const float*)d_in[0];
  const float* Wih = (const float*)d_in[1];
  const float* Whh = (const float*)d_in[2];
  const float* bih = (const float*)d_in[3];
  const float* bhh = (const float*)d_in[4];
  float* out = (float*)d_out;

  xproj_gemm<<<dim3((NB * NS / BM) * (NH / BN)), dim3(256), 0, stream>>>(
      x, Wih, bih, bhh, out);

  const int dyn_lds = KQ * 512 * sizeof(f16x8);   // 80KB
  hipFuncSetAttribute((const void*)rnn_steps,
                      hipFuncAttributeMaxDynamicSharedMemorySize, dyn_lds);
  rnn_steps<<<dim3(NB), dim3(512), dyn_lds, stream>>>(Whh, out);
}